// Round 8
// baseline (976.717 us; speedup 1.0000x reference)
//
#include <hip/hip_runtime.h>
#include <hip/hip_bf16.h>

typedef unsigned int u32;
typedef unsigned short u16;

#define DIMN 256
#define TLEN 256

// ---------------------------------------------------------------------------
// helpers
// ---------------------------------------------------------------------------
typedef _Float16 half2v __attribute__((ext_vector_type(2)));
typedef _Float16 f16x8  __attribute__((ext_vector_type(8)));
typedef float    f32x4  __attribute__((ext_vector_type(4)));

__device__ __forceinline__ u32 packh2(float lo, float hi) {
    _Float16 l = (_Float16)lo, h = (_Float16)hi;
    u16 lu = __builtin_bit_cast(u16, l);
    u16 hu = __builtin_bit_cast(u16, h);
    return (u32)lu | ((u32)hu << 16);
}

__device__ __forceinline__ float h2lo(u32 v) {
    return (float)__builtin_bit_cast(half2v, v).x;
}
__device__ __forceinline__ float h2hi(u32 v) {
    return (float)__builtin_bit_cast(half2v, v).y;
}

// ---------------------------------------------------------------------------
// prep kernels: build P^T, S^T, W^T (fp32), then pack S/P/W/D as MFMA
// A-fragments.
//   Pt[j*256+i] = P[i][j],  P = D^T F D
//   St[j*256+i] = S[i][j],  S = I - (1/a) D^T (A^T A + lam2 I) D
//   Wt[d*256+i] = W[i][d],  W = (1/a) D^T A^T A
// ---------------------------------------------------------------------------
__global__ void prep1(const float* __restrict__ A, const float* __restrict__ D,
                      const float* __restrict__ F, const float* __restrict__ lam2p,
                      float* __restrict__ FD, float* __restrict__ G,
                      float* __restrict__ AD) {
    int gid = blockIdx.x * 256 + threadIdx.x;
    if (gid < 65536) {                   // FD[k][j] = sum_q F[k][q] D[q][j]
        int k = gid >> 8, j = gid & 255;
        float s = 0.f;
        #pragma unroll 8
        for (int q = 0; q < 256; ++q) s += F[k*256+q] * D[q*256+j];
        FD[gid] = s;
    } else if (gid < 131072) {           // G[p][q] = sum_m A[m][p] A[m][q] + lam2*(p==q)
        int g = gid - 65536; int p = g >> 8, q = g & 255;
        float s = (p == q) ? lam2p[0] : 0.f;
        #pragma unroll 8
        for (int m = 0; m < 64; ++m) s += A[m*256+p] * A[m*256+q];
        G[g] = s;
    } else if (gid < 147456) {           // AD[m][i] = sum_k A[m][k] D[k][i]
        int g = gid - 131072; int m = g >> 8, i = g & 255;
        float s = 0.f;
        #pragma unroll 8
        for (int k = 0; k < 256; ++k) s += A[m*256+k] * D[k*256+i];
        AD[g] = s;
    }
}

__global__ void prep2(const float* __restrict__ A, const float* __restrict__ D,
                      const float* __restrict__ alphap,
                      const float* __restrict__ FD, const float* __restrict__ G,
                      const float* __restrict__ AD,
                      float* __restrict__ Pt, float* __restrict__ GD,
                      float* __restrict__ Wt) {
    int gid = blockIdx.x * 256 + threadIdx.x;
    float inva = 1.0f / alphap[0];
    if (gid < 65536) {                   // Pt[j][i] = sum_k D[k][i] FD[k][j]
        int j = gid >> 8, i = gid & 255;
        float s = 0.f;
        #pragma unroll 8
        for (int k = 0; k < 256; ++k) s += D[k*256+i] * FD[k*256+j];
        Pt[gid] = s;
    } else if (gid < 131072) {           // GD[k][j] = sum_q G[k][q] D[q][j]
        int g = gid - 65536; int k = g >> 8, j = g & 255;
        float s = 0.f;
        #pragma unroll 8
        for (int q = 0; q < 256; ++q) s += G[k*256+q] * D[q*256+j];
        GD[g] = s;
    } else {                             // Wt[d][i] = inva * sum_m AD[m][i] A[m][d]
        int g = gid - 131072; int d = g >> 8, i = g & 255;
        float s = 0.f;
        #pragma unroll 8
        for (int m = 0; m < 64; ++m) s += AD[m*256+i] * A[m*256+d];
        Wt[g] = inva * s;
    }
}

__global__ void prep3(const float* __restrict__ D, const float* __restrict__ GD,
                      const float* __restrict__ alphap, float* __restrict__ St) {
    int gid = blockIdx.x * 256 + threadIdx.x;   // 65536 threads
    int j = gid >> 8, i = gid & 255;
    float inva = 1.0f / alphap[0];
    float s = 0.f;
    #pragma unroll 8
    for (int k = 0; k < 256; ++k) s += D[k*256+i] * GD[k*256+j];
    St[gid] = ((i == j) ? 1.0f : 0.0f) - inva * s;
}

// Pack S, P, W (transposed sources) and D (row-major) as fp16 MFMA
// A-fragments for v_mfma_f32_16x16x32_f16.
// Fragment (tile tau in 0..15, kk in 0..7, lane l):
//   8 fp16 = M[row][k0..k0+8) with row = 16*tau + (l&15), k0 = 32*kk + 8*(l>>4)
// stored as uint4 at frag[((tau*8+kk)*64 + l)*4].
__global__ void prep4(const float* __restrict__ St, const float* __restrict__ Pt,
                      const float* __restrict__ Wt, const float* __restrict__ Dm,
                      u32* __restrict__ Sfrag, u32* __restrict__ Pfrag,
                      u32* __restrict__ Wfrag, u32* __restrict__ Dfrag) {
    int gid = blockIdx.x * 256 + threadIdx.x;   // 32768 threads
    int sel = gid >> 13;
    int idx = gid & 8191;
    int l   = idx & 63;
    int kk  = (idx >> 6) & 7;
    int tau = idx >> 9;
    int row = 16*tau + (l & 15);
    int k0  = 32*kk + 8*(l >> 4);
    uint4 v;
    if (sel == 3) {   // D is row-major: A[n][d] = Dm[n*256+d]
        float4 fa = *(const float4*)&Dm[row*256 + k0];
        float4 fb = *(const float4*)&Dm[row*256 + k0 + 4];
        v.x = packh2(fa.x, fa.y);
        v.y = packh2(fa.z, fa.w);
        v.z = packh2(fb.x, fb.y);
        v.w = packh2(fb.z, fb.w);
        *(uint4*)&Dfrag[idx*4] = v;
        return;
    }
    const float* M = (sel == 0) ? St : (sel == 1) ? Pt : Wt;
    u32* O = (sel == 0) ? Sfrag : (sel == 1) ? Pfrag : Wfrag;
    v.x = packh2(M[(k0+0)*256 + row], M[(k0+1)*256 + row]);
    v.y = packh2(M[(k0+2)*256 + row], M[(k0+3)*256 + row]);
    v.z = packh2(M[(k0+4)*256 + row], M[(k0+5)*256 + row]);
    v.w = packh2(M[(k0+6)*256 + row], M[(k0+7)*256 + row]);
    *(uint4*)&O[idx*4] = v;
}

// ---------------------------------------------------------------------------
// zgemm2 (MFMA): Z[b][t][i] = sum_d W[i][d] y[b][d][t], written PACKED fp16:
//   Zh[(b*256+t)*128 + i/2] = (Z[..][i_even], Z[..][i_even+1])
// ---------------------------------------------------------------------------
__global__ __attribute__((amdgpu_flat_work_group_size(512, 512),
                          amdgpu_waves_per_eu(2)))
void zgemm2(const float* __restrict__ y, const u32* __restrict__ Wfrag,
            u32* __restrict__ Zh) {
    __shared__ u32 yl[16384];   // 64 KB: [t_local 0..127][dq 0..127] swizzled
    const int tid = threadIdx.x;
    const int l   = tid & 63;
    const int w   = tid >> 6;
    const int g   = l >> 4;
    const int c   = l & 15;
    const int b   = blockIdx.x;
    const int t0  = blockIdx.y * 128;

    // stage y -> fp16 LDS (transpose [d][t] -> [t][d/2] pairs)
    #pragma unroll
    for (int it = 0; it < 8; ++it) {
        int idx = it * 512 + tid;          // [0, 4096)
        int dp = idx >> 5;                 // d-pair 0..127
        int tq = idx & 31;                 // t-quad 0..31
        const float* yb = y + ((size_t)b*256 + 2*dp)*256 + t0 + 4*tq;
        float4 fa = *(const float4*)yb;
        float4 fb = *(const float4*)(yb + 256);
        const float* fav = (const float*)&fa;
        const float* fbv = (const float*)&fb;
        #pragma unroll
        for (int j = 0; j < 4; ++j) {
            int tl = 4*tq + j;
            yl[tl*128 + (dp ^ ((tl & 7) << 2))] = packh2(fav[j], fbv[j]);
        }
    }

    // A-fragments: W, tiles tau = 2w, 2w+1, all 8 kk
    f16x8 Wf0[8], Wf1[8];
    #pragma unroll
    for (int kk = 0; kk < 8; ++kk) {
        Wf0[kk] = __builtin_bit_cast(f16x8, *(const uint4*)&Wfrag[(((2*w+0)*8 + kk)*64 + l)*4]);
        Wf1[kk] = __builtin_bit_cast(f16x8, *(const uint4*)&Wfrag[(((2*w+1)*8 + kk)*64 + l)*4]);
    }
    __syncthreads();

    f32x4 acc0[8], acc1[8];
    #pragma unroll
    for (int tt = 0; tt < 8; ++tt) {
        acc0[tt] = (f32x4){0.f,0.f,0.f,0.f};
        acc1[tt] = (f32x4){0.f,0.f,0.f,0.f};
    }
    const int swz = (c & 7) << 2;
    #pragma unroll
    for (int tt = 0; tt < 8; ++tt) {
        const int tl = 16*tt + c;
        #pragma unroll
        for (int kk = 0; kk < 8; ++kk) {
            int idx = tl*128 + ((16*kk + 4*g) ^ swz);
            f16x8 bf = __builtin_bit_cast(f16x8, *(const uint4*)&yl[idx]);
            acc0[tt] = __builtin_amdgcn_mfma_f32_16x16x32_f16(Wf0[kk], bf, acc0[tt], 0, 0, 0);
            acc1[tt] = __builtin_amdgcn_mfma_f32_16x16x32_f16(Wf1[kk], bf, acc1[tt], 0, 0, 0);
        }
    }
    // epilogue: uint2 pairs at Zh[(b*256+t)*128 + 8*tau + 2g]
    #pragma unroll
    for (int tt = 0; tt < 8; ++tt) {
        const int t = t0 + 16*tt + c;
        uint2 p0, p1;
        p0.x = packh2(acc0[tt][0], acc0[tt][1]);
        p0.y = packh2(acc0[tt][2], acc0[tt][3]);
        p1.x = packh2(acc1[tt][0], acc1[tt][1]);
        p1.y = packh2(acc1[tt][2], acc1[tt][3]);
        u32* zp = &Zh[((size_t)(b*256 + t))*128 + 16*w + 2*g];
        *(uint2*)(zp)     = p0;
        *(uint2*)(zp + 8) = p1;
    }
}

// ---------------------------------------------------------------------------
// scan12: 5-round MFMA scan, 4 waves x 4 tiles (256 threads/block).
// Halves the per-CU LDS h-read stream vs the 8-wave version (32 ds_read_b128
// per round instead of 64) - LDS was 69% of the step at 8 waves. MFMA issue
// per SIMD is unchanged (1 wave x 32 = 2 waves x 16). S,P fragments only
// (Q dropped: 3 matrices would need ~500 regs at 4 tiles/wave; 2 need ~380).
//   round P: a = P h_prev -> h_iter0 (unthresholded); const = Z + c2*a
//   rounds 1-4: h = soft(S h + const); round 4 stores H packed fp16.
// Wave w owns rows 64w..64w+63 (tiles 4w..4w+3). 5 barriers/step.
// Buffer ping-pong identical to scan8 (proven).
// ---------------------------------------------------------------------------
__global__ __attribute__((amdgpu_flat_work_group_size(256, 256),
                          amdgpu_waves_per_eu(1, 1)))
void scan12(const u32* __restrict__ Sfrag, const u32* __restrict__ Pfrag,
            const u32* __restrict__ Zh,
            const float* __restrict__ h0, const float* __restrict__ U,
            const float* __restrict__ lam1p, const float* __restrict__ lam2p,
            const float* __restrict__ alphap,
            u32* __restrict__ Hh) {
    __shared__ __align__(16) u32 hx[2 * 2048];   // 2 x 8 KB h B-fragment buffers

    const int tid = threadIdx.x;       // 0..255
    const int l   = tid & 63;
    const int w   = tid >> 6;          // wave 0..3
    const int lb  = l & 15;            // batch-in-group == MFMA col
    const int g   = l >> 4;            // 0..3
    const int b   = blockIdx.x * 16 + lb;

    const float inva = 1.0f / alphap[0];
    const float bt   = lam1p[0] * inva;
    const float c2   = lam2p[0] * inva;

    // thresholds: 4 tiles x 4 rows per lane; rows = 16*(4w+T) + 4g + r
    float uu[4][4];
    #pragma unroll
    for (int T = 0; T < 4; ++T) {
        int rb = 16*(4*w + T) + 4*g;
        #pragma unroll
        for (int r = 0; r < 4; ++r) uu[T][r] = U[rb + r] * bt;
    }

    // A-fragments: S,P for tiles 4w..4w+3 (AGPR-resident; MFMA reads native)
    f16x8 Sf[4][8], Pf[4][8];
    #pragma unroll
    for (int T = 0; T < 4; ++T) {
        #pragma unroll
        for (int kk = 0; kk < 8; ++kk) {
            Sf[T][kk] = __builtin_bit_cast(f16x8, *(const uint4*)&Sfrag[(((4*w+T)*8 + kk)*64 + l)*4]);
            Pf[T][kk] = __builtin_bit_cast(f16x8, *(const uint4*)&Pfrag[(((4*w+T)*8 + kk)*64 + l)*4]);
        }
    }

    // init h_prev B-fragments into buf0 (h0 is batch-independent):
    // 512 uint4 slots, 256 threads -> 2 each; same mapping as the 8-wave init.
    #pragma unroll
    for (int ii = 0; ii < 2; ++ii) {
        int idx = tid + 256*ii;
        int k0 = 32*(idx >> 6) + 8*((idx & 63) >> 4);
        uint4 hv;
        hv.x = packh2(h0[k0+0], h0[k0+1]);
        hv.y = packh2(h0[k0+2], h0[k0+3]);
        hv.z = packh2(h0[k0+4], h0[k0+5]);
        hv.w = packh2(h0[k0+6], h0[k0+7]);
        *(uint4*)&hx[idx*4] = hv;
    }
    __syncthreads();

    // Z/H: uint2 at base + t*128 + 8*T covers i = 16*(4w+T) + 4g + {0..3}
    const u32* Zb  = Zh + (size_t)b*32768 + 32*w + 2*g;
    u32*       Hbh = Hh + (size_t)b*32768 + 32*w + 2*g;

    // LDS write slot for tile T's 4 values (rows r0..r0+3, r0 = 16*(4w+T)+4g):
    //   kk = r0>>5 = 2w + (T>>1); lane'' = (2*(T&1) + (g>>1))*16 + lb;
    //   word pair offset = (g&1)*2
    int wslot[4];
    #pragma unroll
    for (int T = 0; T < 4; ++T)
        wslot[T] = (2*w + (T >> 1))*256 + ((2*(T & 1) + (g >> 1))*16 + lb)*4 + (g & 1)*2;

    uint2 z[4];
    #pragma unroll
    for (int T = 0; T < 4; ++T) z[T] = *(const uint2*)&Zb[8*T];

    int ro = 0, wo = 2048;

    #pragma unroll 1
    for (int t = 0; t < TLEN; ++t) {
        // ---- P-round: a = P h_prev ----
        f16x8 hb[8];
        #pragma unroll
        for (int kk = 0; kk < 8; ++kk)
            hb[kk] = __builtin_bit_cast(f16x8, *(const uint4*)&hx[ro + (kk*64 + l)*4]);
        f32x4 a[4];
        #pragma unroll
        for (int T = 0; T < 4; ++T) a[T] = (f32x4){0.f,0.f,0.f,0.f};
        #pragma unroll
        for (int kk = 0; kk < 8; ++kk) {
            #pragma unroll
            for (int T = 0; T < 4; ++T)
                a[T] = __builtin_amdgcn_mfma_f32_16x16x32_f16(Pf[T][kk], hb[kk], a[T], 0, 0, 0);
        }
        // h_iter0 = Ph (unthresholded)
        #pragma unroll
        for (int T = 0; T < 4; ++T)
            *(uint2*)&hx[wo + wslot[T]] = make_uint2(packh2(a[T][0], a[T][1]),
                                                     packh2(a[T][2], a[T][3]));
        __syncthreads();

        // Z prefetch for t+1 (drains ~1 round later; fully hidden)
        const int tn = (t < TLEN-1) ? t + 1 : t;
        uint2 zn[4];
        #pragma unroll
        for (int T = 0; T < 4; ++T) zn[T] = *(const uint2*)&Zb[(size_t)tn*128 + 8*T];

        // const = Z + c2 * (P h_prev)  (hides under round-1 ds_reads)
        float cc[4][4];
        #pragma unroll
        for (int T = 0; T < 4; ++T) {
            cc[T][0] = h2lo(z[T].x) + c2*a[T][0];
            cc[T][1] = h2hi(z[T].x) + c2*a[T][1];
            cc[T][2] = h2lo(z[T].y) + c2*a[T][2];
            cc[T][3] = h2hi(z[T].y) + c2*a[T][3];
        }
        int rr = wo, ww = ro;

        // ---- 4 S-rounds: h = soft(S h + const) ----
        #pragma unroll
        for (int it = 0; it < 4; ++it) {
            #pragma unroll
            for (int kk = 0; kk < 8; ++kk)
                hb[kk] = __builtin_bit_cast(f16x8, *(const uint4*)&hx[rr + (kk*64 + l)*4]);
            f32x4 s[4];
            #pragma unroll
            for (int T = 0; T < 4; ++T) s[T] = (f32x4){cc[T][0], cc[T][1], cc[T][2], cc[T][3]};
            #pragma unroll
            for (int kk = 0; kk < 8; ++kk) {
                #pragma unroll
                for (int T = 0; T < 4; ++T)
                    s[T] = __builtin_amdgcn_mfma_f32_16x16x32_f16(Sf[T][kk], hb[kk], s[T], 0, 0, 0);
            }
            float hv[4][4];
            #pragma unroll
            for (int T = 0; T < 4; ++T) {
                #pragma unroll
                for (int r = 0; r < 4; ++r) {
                    float v = s[T][r];
                    float av = fabsf(v) - uu[T][r];
                    hv[T][r] = (av > 0.f) ? copysignf(av, v) : 0.f;
                }
            }
            uint2 pk[4];
            #pragma unroll
            for (int T = 0; T < 4; ++T) {
                pk[T] = make_uint2(packh2(hv[T][0], hv[T][1]), packh2(hv[T][2], hv[T][3]));
                *(uint2*)&hx[ww + wslot[T]] = pk[T];
            }
            __syncthreads();
            if (it == 3) {   // fire-and-forget fp16 H store; drains next P-round
                #pragma unroll
                for (int T = 0; T < 4; ++T)
                    *(uint2*)&Hbh[(size_t)t*128 + 8*T] = pk[T];
            }
            int tmp = rr; rr = ww; ww = tmp;
        }
        ro = rr; wo = ww;    // rr holds final h_t -> next step's h_prev
        #pragma unroll
        for (int T = 0; T < 4; ++T) z[T] = zn[T];
    }
}

// ---------------------------------------------------------------------------
// ogemm2 (MFMA): out[b][n][t] = sum_d D[n][d] * H[b][t][d], H packed fp16.
// ---------------------------------------------------------------------------
__global__ __attribute__((amdgpu_flat_work_group_size(512, 512),
                          amdgpu_waves_per_eu(2)))
void ogemm2(const u32* __restrict__ Dfrag, const u32* __restrict__ Hh,
            float* __restrict__ out) {
    __shared__ u32 hl[16384];   // 64 KB: [t_local][dq] swizzled
    const int tid = threadIdx.x;
    const int l   = tid & 63;
    const int w   = tid >> 6;
    const int g   = l >> 4;
    const int c   = l & 15;
    const int b   = blockIdx.x;
    const int t0  = blockIdx.y * 128;

    // stage H (already fp16-packed): swizzled uint4 copy
    const uint4* Hg = (const uint4*)(Hh + (size_t)b*32768 + (size_t)t0*128);
    #pragma unroll
    for (int it = 0; it < 8; ++it) {
        int j4 = it * 512 + tid;           // uint4 index [0,4096)
        int tl = j4 >> 5, m = j4 & 31;
        ((uint4*)hl)[tl*32 + (m ^ (tl & 7))] = Hg[j4];
    }

    // A-fragments: D, tiles tau = 2w, 2w+1
    f16x8 Df0[8], Df1[8];
    #pragma unroll
    for (int kk = 0; kk < 8; ++kk) {
        Df0[kk] = __builtin_bit_cast(f16x8, *(const uint4*)&Dfrag[(((2*w+0)*8 + kk)*64 + l)*4]);
        Df1[kk] = __builtin_bit_cast(f16x8, *(const uint4*)&Dfrag[(((2*w+1)*8 + kk)*64 + l)*4]);
    }
    __syncthreads();

    f32x4 acc0[8], acc1[8];
    #pragma unroll
    for (int tt = 0; tt < 8; ++tt) {
        acc0[tt] = (f32x4){0.f,0.f,0.f,0.f};
        acc1[tt] = (f32x4){0.f,0.f,0.f,0.f};
    }
    const int swz = (c & 7) << 2;
    #pragma unroll
    for (int tt = 0; tt < 8; ++tt) {
        const int tl = 16*tt + c;
        #pragma unroll
        for (int kk = 0; kk < 8; ++kk) {
            int idx = tl*128 + ((16*kk + 4*g) ^ swz);
            f16x8 bf = __builtin_bit_cast(f16x8, *(const uint4*)&hl[idx]);
            acc0[tt] = __builtin_amdgcn_mfma_f32_16x16x32_f16(Df0[kk], bf, acc0[tt], 0, 0, 0);
            acc1[tt] = __builtin_amdgcn_mfma_f32_16x16x32_f16(Df1[kk], bf, acc1[tt], 0, 0, 0);
        }
    }
    // epilogue: out[b][n][t], n = 16*tau + 4g + r, t = t0 + 16tt + c
    #pragma unroll
    for (int tt = 0; tt < 8; ++tt) {
        const int t = t0 + 16*tt + c;
        const int n0 = 16*(2*w+0) + 4*g;
        const int n1 = 16*(2*w+1) + 4*g;
        #pragma unroll
        for (int r = 0; r < 4; ++r) {
            out[((size_t)(b*256) + n0 + r)*256 + t] = acc0[tt][r];
            out[((size_t)(b*256) + n1 + r)*256 + t] = acc1[tt][r];
        }
    }
}

// ---------------------------------------------------------------------------
extern "C" void kernel_launch(void* const* d_in, const int* in_sizes, int n_in,
                              void* d_out, int out_size, void* d_ws, size_t ws_size,
                              hipStream_t stream) {
    const float* y     = (const float*)d_in[0];
    const float* A     = (const float*)d_in[1];
    const float* D     = (const float*)d_in[2];
    const float* F     = (const float*)d_in[3];
    const float* lam1  = (const float*)d_in[4];
    const float* lam2  = (const float*)d_in[5];
    const float* alpha = (const float*)d_in[6];
    const float* h0    = (const float*)d_in[7];
    const float* U     = (const float*)d_in[8];
    float* out = (float*)d_out;
    float* ws  = (float*)d_ws;

    // ws layout (fp32-element offsets)
    const size_t oZ  = 0;           // Zh u32 (8.39M region 16.7M)
    const size_t oH  = 16777216;    // Hh u32 packed fp16 (8.39M of 16.7M region)
    const size_t oWt = 33554432;
    const size_t oSt = 33619968;
    const size_t oPt = 33685504;
    const size_t oFD = 33751040;
    const size_t oG  = 33816576;
    const size_t oGD = 33882112;    // GD during prep2/3; Wfrag+Dfrag afterwards
    const size_t oAD = 33947648;
    const size_t oSh = 33964032;   // Sfrag u32 (32768)
    const size_t oPh = 33996800;   // Pfrag u32 (32768)

    u32*   Zh = (u32*)(ws + oZ);
    u32*   Hh = (u32*)(ws + oH);
    float* Wt = ws + oWt; float* St = ws + oSt; float* Pt = ws + oPt;
    float* FD = ws + oFD; float* G  = ws + oG;  float* GD = ws + oGD;
    float* AD = ws + oAD;
    u32* Sfrag = (u32*)(ws + oSh);
    u32* Pfrag = (u32*)(ws + oPh);
    u32* Wfrag = (u32*)(ws + oGD);            // reuse GD region (dead after prep3)
    u32* Dfrag = (u32*)(ws + oGD + 32768);    // second half of GD region

    prep1<<<576, 256, 0, stream>>>(A, D, F, lam2, FD, G, AD);
    prep2<<<768, 256, 0, stream>>>(A, D, alpha, FD, G, AD, Pt, GD, Wt);
    prep3<<<256, 256, 0, stream>>>(D, GD, alpha, St);
    prep4<<<128, 256, 0, stream>>>(St, Pt, Wt, D, Sfrag, Pfrag, Wfrag, Dfrag);
    {
        dim3 gz(256, 2);
        zgemm2<<<gz, 512, 0, stream>>>(y, Wfrag, Zh);
    }
    scan12<<<16, 256, 0, stream>>>(Sfrag, Pfrag, Zh, h0, U, lam1, lam2, alpha, Hh);
    {
        dim3 go(256, 2);
        ogemm2<<<go, 512, 0, stream>>>(Dfrag, Hh, out);
    }
}

// Round 10
// 791.801 us; speedup vs baseline: 1.2335x; 1.2335x over previous
//
#include <hip/hip_runtime.h>
#include <hip/hip_bf16.h>

typedef unsigned int u32;
typedef unsigned short u16;

#define DIMN 256
#define TLEN 256

// ---------------------------------------------------------------------------
// helpers
// ---------------------------------------------------------------------------
typedef _Float16 half2v __attribute__((ext_vector_type(2)));
typedef _Float16 f16x8  __attribute__((ext_vector_type(8)));
typedef float    f32x4  __attribute__((ext_vector_type(4)));

__device__ __forceinline__ u32 packh2(float lo, float hi) {
    _Float16 l = (_Float16)lo, h = (_Float16)hi;
    u16 lu = __builtin_bit_cast(u16, l);
    u16 hu = __builtin_bit_cast(u16, h);
    return (u32)lu | ((u32)hu << 16);
}

__device__ __forceinline__ float h2lo(u32 v) {
    return (float)__builtin_bit_cast(half2v, v).x;
}
__device__ __forceinline__ float h2hi(u32 v) {
    return (float)__builtin_bit_cast(half2v, v).y;
}

// u32 slot inside a frag array for element pair (row=i, k=2*jp, 2*jp+1).
// Inverse of the prep4 forward map (verified: i=37,jp=49 -> 4885 both ways):
//   idx = (tau*8+kk)*64 + l, word m;  tau=i>>4, kk=jp>>4, l=((jp>>2)&3)*16+(i&15),
//   m = jp&3.
__device__ __forceinline__ int frag_addr(int i, int jp) {
    return ((((i >> 4) * 8 + (jp >> 4)) * 64) + ((jp >> 2) & 3) * 16 + (i & 15)) * 4
           + (jp & 3);
}

// ---------------------------------------------------------------------------
// prep kernels: build P^T, S^T (fp32) and pack S/P/Q/W/D fp16 MFMA A-fragments
// INLINE in the producing kernels (prep4 eliminated).
//   Pt[j*256+i] = P[i][j],  P = D^T F D
//   St[j*256+i] = S[i][j],  S = I - (1/a) D^T (A^T A + lam2 I) D
//   W[i][d] = (1/a) (D^T A^T A)[i][d]   (frag-only)
//   Q = (S + c2 I) P                    (frag-only)
// Fragment (tile tau, kk, lane l): 8 fp16 = M[row][k0..k0+8),
//   row = 16*tau + (l&15), k0 = 32*kk + 8*(l>>4); frag k-dim: j for S/P/Q,
//   d for W/D.
// ---------------------------------------------------------------------------
__global__ void prep1(const float* __restrict__ A, const float* __restrict__ D,
                      const float* __restrict__ F, const float* __restrict__ lam2p,
                      float* __restrict__ FD, float* __restrict__ G,
                      float* __restrict__ AD) {
    int gid = blockIdx.x * 256 + threadIdx.x;
    if (gid < 65536) {                   // FD[k][j] = sum_q F[k][q] D[q][j]
        int k = gid >> 8, j = gid & 255;
        float s = 0.f;
        #pragma unroll 8
        for (int q = 0; q < 256; ++q) s += F[k*256+q] * D[q*256+j];
        FD[gid] = s;
    } else if (gid < 131072) {           // G[p][q] = sum_m A[m][p] A[m][q] + lam2*(p==q)
        int g = gid - 65536; int p = g >> 8, q = g & 255;
        float s = (p == q) ? lam2p[0] : 0.f;
        #pragma unroll 8
        for (int m = 0; m < 64; ++m) s += A[m*256+p] * A[m*256+q];
        G[g] = s;
    } else if (gid < 147456) {           // AD[m][i] = sum_k A[m][k] D[k][i]
        int g = gid - 131072; int m = g >> 8, i = g & 255;
        float s = 0.f;
        #pragma unroll 8
        for (int k = 0; k < 256; ++k) s += A[m*256+k] * D[k*256+i];
        AD[g] = s;
    }
}

// prep2: Pt (+Pfrag inline), GD, Wfrag inline.  131072 threads.
__global__ void prep2(const float* __restrict__ A, const float* __restrict__ D,
                      const float* __restrict__ alphap,
                      const float* __restrict__ FD, const float* __restrict__ G,
                      const float* __restrict__ AD,
                      float* __restrict__ Pt, float* __restrict__ GD,
                      u32* __restrict__ Pfrag, u32* __restrict__ Wfrag) {
    int gid = blockIdx.x * 256 + threadIdx.x;
    float inva = 1.0f / alphap[0];
    if (gid < 32768) {                   // Pt pair: i lanes, jp block-uniform
        int i = gid & 255, jp = gid >> 8;
        int j0 = 2*jp, j1 = 2*jp + 1;
        float s0 = 0.f, s1 = 0.f;
        #pragma unroll 8
        for (int k = 0; k < 256; ++k) {
            float dv = D[k*256+i];
            s0 += dv * FD[k*256+j0];
            s1 += dv * FD[k*256+j1];
        }
        Pt[j0*256+i] = s0;
        Pt[j1*256+i] = s1;
        Pfrag[frag_addr(i, jp)] = packh2(s0, s1);
    } else if (gid < 98304) {            // GD[k][j] = sum_q G[k][q] D[q][j]
        int g = gid - 32768; int k = g >> 8, j = g & 255;
        float s = 0.f;
        #pragma unroll 8
        for (int q = 0; q < 256; ++q) s += G[k*256+q] * D[q*256+j];
        GD[g] = s;
    } else {                             // W pair: W[i][d] = inva*sum_m AD[m][i] A[m][d]
        int g = gid - 98304; int i = g & 255, dp = g >> 8;
        int d0 = 2*dp, d1 = 2*dp + 1;
        float s0 = 0.f, s1 = 0.f;
        #pragma unroll 8
        for (int m = 0; m < 64; ++m) {
            float av = AD[m*256+i];
            s0 += av * A[m*256+d0];
            s1 += av * A[m*256+d1];
        }
        Wfrag[frag_addr(i, dp)] = packh2(inva*s0, inva*s1);
    }
}

// prep3: St pair (+Sfrag inline).  32768 threads.
__global__ void prep3(const float* __restrict__ D, const float* __restrict__ GD,
                      const float* __restrict__ alphap,
                      float* __restrict__ St, u32* __restrict__ Sfrag) {
    int gid = blockIdx.x * 256 + threadIdx.x;
    int i = gid & 255, jp = gid >> 8;
    int j0 = 2*jp, j1 = 2*jp + 1;
    float inva = 1.0f / alphap[0];
    float s0 = 0.f, s1 = 0.f;
    #pragma unroll 8
    for (int k = 0; k < 256; ++k) {
        float dv = D[k*256+i];
        s0 += dv * GD[k*256+j0];
        s1 += dv * GD[k*256+j1];
    }
    float v0 = ((i == j0) ? 1.0f : 0.0f) - inva * s0;
    float v1 = ((i == j1) ? 1.0f : 0.0f) - inva * s1;
    St[j0*256+i] = v0;
    St[j1*256+i] = v1;
    Sfrag[frag_addr(i, jp)] = packh2(v0, v1);
}

// prep5: Qfrag pair (Q = (S + c2 I) P, no Qt array) + Dfrag pack.  40960 thr.
__global__ void prep5(const float* __restrict__ St, const float* __restrict__ Pt,
                      const float* __restrict__ Dm,
                      const float* __restrict__ lam2p, const float* __restrict__ alphap,
                      u32* __restrict__ Qfrag, u32* __restrict__ Dfrag) {
    int gid = blockIdx.x * 256 + threadIdx.x;
    if (gid < 32768) {
        int i = gid & 255, jp = gid >> 8;
        int j0 = 2*jp, j1 = 2*jp + 1;
        float c2 = lam2p[0] / alphap[0];
        float s0 = c2 * Pt[j0*256 + i];
        float s1 = c2 * Pt[j1*256 + i];
        #pragma unroll 8
        for (int k = 0; k < 256; ++k) {
            float sv = St[k*256+i];
            s0 += sv * Pt[j0*256+k];
            s1 += sv * Pt[j1*256+k];
        }
        Qfrag[frag_addr(i, jp)] = packh2(s0, s1);
    } else {                             // Dfrag: row-major D, A[n][d] = Dm[n*256+d]
        int idx = gid - 32768;           // [0, 8192)
        int l   = idx & 63;
        int kk  = (idx >> 6) & 7;
        int tau = idx >> 9;
        int row = 16*tau + (l & 15);
        int k0  = 32*kk + 8*(l >> 4);
        float4 fa = *(const float4*)&Dm[row*256 + k0];
        float4 fb = *(const float4*)&Dm[row*256 + k0 + 4];
        uint4 v;
        v.x = packh2(fa.x, fa.y);
        v.y = packh2(fa.z, fa.w);
        v.z = packh2(fb.x, fb.y);
        v.w = packh2(fb.z, fb.w);
        *(uint4*)&Dfrag[idx*4] = v;
    }
}

// ---------------------------------------------------------------------------
// zgemm2 (MFMA): Z[b][t][i] = sum_d W[i][d] y[b][d][t], written PACKED fp16:
//   Zh[(b*256+t)*128 + i/2] = (Z[..][i_even], Z[..][i_even+1])
// ---------------------------------------------------------------------------
__global__ __attribute__((amdgpu_flat_work_group_size(512, 512),
                          amdgpu_waves_per_eu(2)))
void zgemm2(const float* __restrict__ y, const u32* __restrict__ Wfrag,
            u32* __restrict__ Zh) {
    __shared__ u32 yl[16384];   // 64 KB: [t_local 0..127][dq 0..127] swizzled
    const int tid = threadIdx.x;
    const int l   = tid & 63;
    const int w   = tid >> 6;
    const int g   = l >> 4;
    const int c   = l & 15;
    const int b   = blockIdx.x;
    const int t0  = blockIdx.y * 128;

    // stage y -> fp16 LDS (transpose [d][t] -> [t][d/2] pairs)
    #pragma unroll
    for (int it = 0; it < 8; ++it) {
        int idx = it * 512 + tid;          // [0, 4096)
        int dp = idx >> 5;                 // d-pair 0..127
        int tq = idx & 31;                 // t-quad 0..31
        const float* yb = y + ((size_t)b*256 + 2*dp)*256 + t0 + 4*tq;
        float4 fa = *(const float4*)yb;
        float4 fb = *(const float4*)(yb + 256);
        const float* fav = (const float*)&fa;
        const float* fbv = (const float*)&fb;
        #pragma unroll
        for (int j = 0; j < 4; ++j) {
            int tl = 4*tq + j;
            yl[tl*128 + (dp ^ ((tl & 7) << 2))] = packh2(fav[j], fbv[j]);
        }
    }

    // A-fragments: W, tiles tau = 2w, 2w+1, all 8 kk
    f16x8 Wf0[8], Wf1[8];
    #pragma unroll
    for (int kk = 0; kk < 8; ++kk) {
        Wf0[kk] = __builtin_bit_cast(f16x8, *(const uint4*)&Wfrag[(((2*w+0)*8 + kk)*64 + l)*4]);
        Wf1[kk] = __builtin_bit_cast(f16x8, *(const uint4*)&Wfrag[(((2*w+1)*8 + kk)*64 + l)*4]);
    }
    __syncthreads();

    f32x4 acc0[8], acc1[8];
    #pragma unroll
    for (int tt = 0; tt < 8; ++tt) {
        acc0[tt] = (f32x4){0.f,0.f,0.f,0.f};
        acc1[tt] = (f32x4){0.f,0.f,0.f,0.f};
    }
    const int swz = (c & 7) << 2;
    #pragma unroll
    for (int tt = 0; tt < 8; ++tt) {
        const int tl = 16*tt + c;
        #pragma unroll
        for (int kk = 0; kk < 8; ++kk) {
            int idx = tl*128 + ((16*kk + 4*g) ^ swz);
            f16x8 bf = __builtin_bit_cast(f16x8, *(const uint4*)&yl[idx]);
            acc0[tt] = __builtin_amdgcn_mfma_f32_16x16x32_f16(Wf0[kk], bf, acc0[tt], 0, 0, 0);
            acc1[tt] = __builtin_amdgcn_mfma_f32_16x16x32_f16(Wf1[kk], bf, acc1[tt], 0, 0, 0);
        }
    }
    // epilogue: uint2 pairs at Zh[(b*256+t)*128 + 8*tau + 2g]
    #pragma unroll
    for (int tt = 0; tt < 8; ++tt) {
        const int t = t0 + 16*tt + c;
        uint2 p0, p1;
        p0.x = packh2(acc0[tt][0], acc0[tt][1]);
        p0.y = packh2(acc0[tt][2], acc0[tt][3]);
        p1.x = packh2(acc1[tt][0], acc1[tt][1]);
        p1.y = packh2(acc1[tt][2], acc1[tt][3]);
        u32* zp = &Zh[((size_t)(b*256 + t))*128 + 16*w + 2*g];
        *(uint2*)(zp)     = p0;
        *(uint2*)(zp + 8) = p1;
    }
}

// ---------------------------------------------------------------------------
// scan9: 4-round MFMA scan via Q-fusion (PROVEN 588us structure - verbatim).
//   round A: h1 = soft(Q h_prev + Z)   AND   const = Z + c2 * (P h_prev)
//   rounds B,C,D: h = soft(S h + const);  D stores H packed fp16.
// 16 blocks x 512 threads; wave w owns rows 32w..32w+31 (tiles 2w, 2w+1).
// ---------------------------------------------------------------------------
__global__ __attribute__((amdgpu_flat_work_group_size(512, 512),
                          amdgpu_waves_per_eu(2, 2)))
void scan9(const u32* __restrict__ Sfrag, const u32* __restrict__ Pfrag,
           const u32* __restrict__ Qfrag,
           const u32* __restrict__ Zh,
           const float* __restrict__ h0, const float* __restrict__ U,
           const float* __restrict__ lam1p, const float* __restrict__ lam2p,
           const float* __restrict__ alphap,
           u32* __restrict__ Hh) {
    __shared__ __align__(16) u32 hx[2 * 2048];   // 2 x 8 KB h B-fragment buffers

    const int tid = threadIdx.x;
    const int l   = tid & 63;
    const int w   = tid >> 6;          // wave 0..7
    const int lb  = l & 15;            // batch-in-group == MFMA col
    const int g   = l >> 4;            // 0..3
    const int b   = blockIdx.x * 16 + lb;

    const float inva = 1.0f / alphap[0];
    const float bt   = lam1p[0] * inva;
    const float c2   = lam2p[0] * inva;

    // per-lane rows: 32w + 16T + 4g + r
    const int rb = 32*w + 4*g;
    const float u00 = U[rb+0]*bt,  u01 = U[rb+1]*bt,  u02 = U[rb+2]*bt,  u03 = U[rb+3]*bt;
    const float u10 = U[rb+16]*bt, u11 = U[rb+17]*bt, u12 = U[rb+18]*bt, u13 = U[rb+19]*bt;

    // A-fragments -> AGPR-backed registers (coalesced uint4 loads)
    f16x8 Sf0[8], Sf1[8], Pf0[8], Pf1[8], Qf0[8], Qf1[8];
    #pragma unroll
    for (int kk = 0; kk < 8; ++kk) {
        Sf0[kk] = __builtin_bit_cast(f16x8, *(const uint4*)&Sfrag[(((2*w+0)*8 + kk)*64 + l)*4]);
        Sf1[kk] = __builtin_bit_cast(f16x8, *(const uint4*)&Sfrag[(((2*w+1)*8 + kk)*64 + l)*4]);
        Pf0[kk] = __builtin_bit_cast(f16x8, *(const uint4*)&Pfrag[(((2*w+0)*8 + kk)*64 + l)*4]);
        Pf1[kk] = __builtin_bit_cast(f16x8, *(const uint4*)&Pfrag[(((2*w+1)*8 + kk)*64 + l)*4]);
        Qf0[kk] = __builtin_bit_cast(f16x8, *(const uint4*)&Qfrag[(((2*w+0)*8 + kk)*64 + l)*4]);
        Qf1[kk] = __builtin_bit_cast(f16x8, *(const uint4*)&Qfrag[(((2*w+1)*8 + kk)*64 + l)*4]);
    }

    // init h_prev B-fragments into buf0 (h0 is batch-independent)
    {
        int k0 = 32*(tid >> 6) + 8*((tid & 63) >> 4);
        uint4 hv;
        hv.x = packh2(h0[k0+0], h0[k0+1]);
        hv.y = packh2(h0[k0+2], h0[k0+3]);
        hv.z = packh2(h0[k0+4], h0[k0+5]);
        hv.w = packh2(h0[k0+6], h0[k0+7]);
        *(uint4*)&hx[tid*4] = hv;
    }
    __syncthreads();

    // Z: uint2 at Zb[t*128 + 8T] covers i = 32w + 16T + 4g + {0..3}
    const u32* Zb = Zh + (size_t)b*32768 + 16*w + 2*g;
    u32* Hbh = Hh + (size_t)b*32768 + 16*w + 2*g;   // same index math as Zb

    // write slot (u32 index inside a buffer) for this lane's tile-T=0 pair;
    // tile-T=1 is +128.  (kk = w slice; lane'' = (2T + (g>>1))*16 + lb)
    const int wb0 = w*256 + (((g>>1))*16 + lb)*4 + (g&1)*2;

    uint2 z0 = *(const uint2*)&Zb[0];
    uint2 z1 = *(const uint2*)&Zb[8];

    #pragma unroll 1
    for (int t = 0; t < TLEN; ++t) {
        // ---- Round A: q = Q h_prev (+Z init), a = P h_prev ----
        f16x8 hb[8];
        #pragma unroll
        for (int kk = 0; kk < 8; ++kk)
            hb[kk] = __builtin_bit_cast(f16x8, *(const uint4*)&hx[0 + (kk*64 + l)*4]);
        f32x4 q0 = {h2lo(z0.x), h2hi(z0.x), h2lo(z0.y), h2hi(z0.y)};
        f32x4 q1 = {h2lo(z1.x), h2hi(z1.x), h2lo(z1.y), h2hi(z1.y)};
        f32x4 a0 = {0.f,0.f,0.f,0.f}, a1 = {0.f,0.f,0.f,0.f};
        #pragma unroll
        for (int kk = 0; kk < 8; ++kk) {
            q0 = __builtin_amdgcn_mfma_f32_16x16x32_f16(Qf0[kk], hb[kk], q0, 0, 0, 0);
            q1 = __builtin_amdgcn_mfma_f32_16x16x32_f16(Qf1[kk], hb[kk], q1, 0, 0, 0);
            a0 = __builtin_amdgcn_mfma_f32_16x16x32_f16(Pf0[kk], hb[kk], a0, 0, 0, 0);
            a1 = __builtin_amdgcn_mfma_f32_16x16x32_f16(Pf1[kk], hb[kk], a1, 0, 0, 0);
        }
        // h1 = soft(q)
        {
            const float h00 = copysignf(fmaxf(fabsf(q0[0]) - u00, 0.f), q0[0]);
            const float h01 = copysignf(fmaxf(fabsf(q0[1]) - u01, 0.f), q0[1]);
            const float h02 = copysignf(fmaxf(fabsf(q0[2]) - u02, 0.f), q0[2]);
            const float h03 = copysignf(fmaxf(fabsf(q0[3]) - u03, 0.f), q0[3]);
            const float h10 = copysignf(fmaxf(fabsf(q1[0]) - u10, 0.f), q1[0]);
            const float h11 = copysignf(fmaxf(fabsf(q1[1]) - u11, 0.f), q1[1]);
            const float h12 = copysignf(fmaxf(fabsf(q1[2]) - u12, 0.f), q1[2]);
            const float h13 = copysignf(fmaxf(fabsf(q1[3]) - u13, 0.f), q1[3]);
            *(uint2*)&hx[2048 + wb0]       = make_uint2(packh2(h00,h01), packh2(h02,h03));
            *(uint2*)&hx[2048 + wb0 + 128] = make_uint2(packh2(h10,h11), packh2(h12,h13));
        }
        __syncthreads();

        // Z prefetch for t+1 (used ~4 rounds from now - fully hidden)
        const int tn = (t < TLEN-1) ? t + 1 : t;
        uint2 zn0 = *(const uint2*)&Zb[(size_t)tn*128];
        uint2 zn1 = *(const uint2*)&Zb[(size_t)tn*128 + 8];

        // const = Z + c2 * (P h_prev)  (off critical path; hides under B's reads)
        const float c00 = h2lo(z0.x) + c2*a0[0];
        const float c01 = h2hi(z0.x) + c2*a0[1];
        const float c02 = h2lo(z0.y) + c2*a0[2];
        const float c03 = h2hi(z0.y) + c2*a0[3];
        const float c10 = h2lo(z1.x) + c2*a1[0];
        const float c11 = h2hi(z1.x) + c2*a1[1];
        const float c12 = h2lo(z1.y) + c2*a1[2];
        const float c13 = h2hi(z1.y) + c2*a1[3];

        // ---- Rounds B,C,D: h = soft(S h + const) ----
        #pragma unroll
        for (int it = 0; it < 3; ++it) {
            const int rd = (it & 1) ? 0 : 2048;
            const int wr = (it & 1) ? 2048 : 0;
            #pragma unroll
            for (int kk = 0; kk < 8; ++kk)
                hb[kk] = __builtin_bit_cast(f16x8, *(const uint4*)&hx[rd + (kk*64 + l)*4]);
            f32x4 s0 = {c00,c01,c02,c03};
            f32x4 s1 = {c10,c11,c12,c13};
            #pragma unroll
            for (int kk = 0; kk < 8; ++kk) {
                s0 = __builtin_amdgcn_mfma_f32_16x16x32_f16(Sf0[kk], hb[kk], s0, 0, 0, 0);
                s1 = __builtin_amdgcn_mfma_f32_16x16x32_f16(Sf1[kk], hb[kk], s1, 0, 0, 0);
            }
            const float h00 = copysignf(fmaxf(fabsf(s0[0]) - u00, 0.f), s0[0]);
            const float h01 = copysignf(fmaxf(fabsf(s0[1]) - u01, 0.f), s0[1]);
            const float h02 = copysignf(fmaxf(fabsf(s0[2]) - u02, 0.f), s0[2]);
            const float h03 = copysignf(fmaxf(fabsf(s0[3]) - u03, 0.f), s0[3]);
            const float h10 = copysignf(fmaxf(fabsf(s1[0]) - u10, 0.f), s1[0]);
            const float h11 = copysignf(fmaxf(fabsf(s1[1]) - u11, 0.f), s1[1]);
            const float h12 = copysignf(fmaxf(fabsf(s1[2]) - u12, 0.f), s1[2]);
            const float h13 = copysignf(fmaxf(fabsf(s1[3]) - u13, 0.f), s1[3]);
            *(uint2*)&hx[wr + wb0]       = make_uint2(packh2(h00,h01), packh2(h02,h03));
            *(uint2*)&hx[wr + wb0 + 128] = make_uint2(packh2(h10,h11), packh2(h12,h13));
            __syncthreads();
            if (it == 2) {   // fire-and-forget fp16 H store; drains next round A
                *(uint2*)&Hbh[(size_t)t*128]     = make_uint2(packh2(h00,h01), packh2(h02,h03));
                *(uint2*)&Hbh[(size_t)t*128 + 8] = make_uint2(packh2(h10,h11), packh2(h12,h13));
            }
        }
        z0 = zn0; z1 = zn1;
    }
}

// ---------------------------------------------------------------------------
// ogemm2 (MFMA): out[b][n][t] = sum_d D[n][d] * H[b][t][d], H packed fp16.
// ---------------------------------------------------------------------------
__global__ __attribute__((amdgpu_flat_work_group_size(512, 512),
                          amdgpu_waves_per_eu(2)))
void ogemm2(const u32* __restrict__ Dfrag, const u32* __restrict__ Hh,
            float* __restrict__ out) {
    __shared__ u32 hl[16384];   // 64 KB: [t_local][dq] swizzled
    const int tid = threadIdx.x;
    const int l   = tid & 63;
    const int w   = tid >> 6;
    const int g   = l >> 4;
    const int c   = l & 15;
    const int b   = blockIdx.x;
    const int t0  = blockIdx.y * 128;

    // stage H (already fp16-packed): swizzled uint4 copy
    const uint4* Hg = (const uint4*)(Hh + (size_t)b*32768 + (size_t)t0*128);
    #pragma unroll
    for (int it = 0; it < 8; ++it) {
        int j4 = it * 512 + tid;           // uint4 index [0,4096)
        int tl = j4 >> 5, m = j4 & 31;
        ((uint4*)hl)[tl*32 + (m ^ (tl & 7))] = Hg[j4];
    }

    // A-fragments: D, tiles tau = 2w, 2w+1
    f16x8 Df0[8], Df1[8];
    #pragma unroll
    for (int kk = 0; kk < 8; ++kk) {
        Df0[kk] = __builtin_bit_cast(f16x8, *(const uint4*)&Dfrag[(((2*w+0)*8 + kk)*64 + l)*4]);
        Df1[kk] = __builtin_bit_cast(f16x8, *(const uint4*)&Dfrag[(((2*w+1)*8 + kk)*64 + l)*4]);
    }
    __syncthreads();

    f32x4 acc0[8], acc1[8];
    #pragma unroll
    for (int tt = 0; tt < 8; ++tt) {
        acc0[tt] = (f32x4){0.f,0.f,0.f,0.f};
        acc1[tt] = (f32x4){0.f,0.f,0.f,0.f};
    }
    const int swz = (c & 7) << 2;
    #pragma unroll
    for (int tt = 0; tt < 8; ++tt) {
        const int tl = 16*tt + c;
        #pragma unroll
        for (int kk = 0; kk < 8; ++kk) {
            int idx = tl*128 + ((16*kk + 4*g) ^ swz);
            f16x8 bf = __builtin_bit_cast(f16x8, *(const uint4*)&hl[idx]);
            acc0[tt] = __builtin_amdgcn_mfma_f32_16x16x32_f16(Df0[kk], bf, acc0[tt], 0, 0, 0);
            acc1[tt] = __builtin_amdgcn_mfma_f32_16x16x32_f16(Df1[kk], bf, acc1[tt], 0, 0, 0);
        }
    }
    // epilogue: out[b][n][t], n = 16*tau + 4g + r, t = t0 + 16tt + c
    #pragma unroll
    for (int tt = 0; tt < 8; ++tt) {
        const int t = t0 + 16*tt + c;
        const int n0 = 16*(2*w+0) + 4*g;
        const int n1 = 16*(2*w+1) + 4*g;
        #pragma unroll
        for (int r = 0; r < 4; ++r) {
            out[((size_t)(b*256) + n0 + r)*256 + t] = acc0[tt][r];
            out[((size_t)(b*256) + n1 + r)*256 + t] = acc1[tt][r];
        }
    }
}

// ---------------------------------------------------------------------------
extern "C" void kernel_launch(void* const* d_in, const int* in_sizes, int n_in,
                              void* d_out, int out_size, void* d_ws, size_t ws_size,
                              hipStream_t stream) {
    const float* y     = (const float*)d_in[0];
    const float* A     = (const float*)d_in[1];
    const float* D     = (const float*)d_in[2];
    const float* F     = (const float*)d_in[3];
    const float* lam1  = (const float*)d_in[4];
    const float* lam2  = (const float*)d_in[5];
    const float* alpha = (const float*)d_in[6];
    const float* h0    = (const float*)d_in[7];
    const float* U     = (const float*)d_in[8];
    float* out = (float*)d_out;
    float* ws  = (float*)d_ws;

    // ws layout (fp32-element offsets) - footprint identical to the proven
    // R5 build (high-water mark 34029568 fp32); Wfrag/Dfrag live in the old
    // Wt region (33554432..33620000), which is otherwise unused now.
    const size_t oZ  = 0;           // Zh u32 (8.39M region 16.7M)
    const size_t oH  = 16777216;    // Hh u32 packed fp16
    const size_t oWf = 33554432;    // Wfrag u32 (32768)   [old Wt region]
    const size_t oDf = 33587200;    // Dfrag u32 (32768)   [old Wt region 2nd half]
    const size_t oSt = 33619968;
    const size_t oPt = 33685504;
    const size_t oFD = 33751040;
    const size_t oG  = 33816576;    // G during prep1/2; Qfrag afterwards (32768 u32)
    const size_t oGD = 33882112;
    const size_t oAD = 33947648;
    const size_t oSh = 33964032;   // Sfrag u32 (32768)
    const size_t oPh = 33996800;   // Pfrag u32 (32768)

    u32*   Zh = (u32*)(ws + oZ);
    u32*   Hh = (u32*)(ws + oH);
    float* St = ws + oSt; float* Pt = ws + oPt;
    float* FD = ws + oFD; float* G  = ws + oG;  float* GD = ws + oGD;
    float* AD = ws + oAD;
    u32* Sfrag = (u32*)(ws + oSh);
    u32* Pfrag = (u32*)(ws + oPh);
    u32* Qfrag = (u32*)(ws + oG);    // reuse G region (dead after prep2)
    u32* Wfrag = (u32*)(ws + oWf);
    u32* Dfrag = (u32*)(ws + oDf);

    prep1<<<576, 256, 0, stream>>>(A, D, F, lam2, FD, G, AD);
    prep2<<<512, 256, 0, stream>>>(A, D, alpha, FD, G, AD, Pt, GD, Pfrag, Wfrag);
    prep3<<<128, 256, 0, stream>>>(D, GD, alpha, St, Sfrag);
    prep5<<<160, 256, 0, stream>>>(St, Pt, D, lam2, alpha, Qfrag, Dfrag);
    {
        dim3 gz(256, 2);
        zgemm2<<<gz, 512, 0, stream>>>(y, Wfrag, Zh);
    }
    scan9<<<16, 512, 0, stream>>>(Sfrag, Pfrag, Qfrag, Zh, h0, U, lam1, lam2, alpha, Hh);
    {
        dim3 go(256, 2);
        ogemm2<<<go, 512, 0, stream>>>(Dfrag, Hh, out);
    }
}